// Round 14
// baseline (367.555 us; speedup 1.0000x reference)
//
#include <hip/hip_runtime.h>
#include <hip/hip_bf16.h>

// Problem constants
#define BB 4
#define SS 12
#define NN 307
#define LL 1228      // B*N
#define BSC 48       // B*S
#define GG 48        // S*HEADS
// Workspace offsets (floats)
#define WS_CX    0           // [3][3][48][307] = 132624
#define WS_CROW  132624      // [3][307]
#define WS_TXD   133568      // [3][64]
#define WS_TBD   133760
#define WS_T1D   133952
#define WS_T2D   134144
#define WS_TOB   134336
#define WS_WRCT  134528      // [64][64] W_rc transposed
#define WS_WOT   138624      // [64][64] W_out transposed
#define WS_H2    142720      // [B][S][N][64] post-FF hidden = 943104
#define WS_TFL   1085824     // [B][64][307] tc_last in (b,f,n) order = 78592
#define WS_XFL   1164416     // [B][S][64][307] emb_x; REUSED by k7a as comb[L][S][64]
#define WS_QH    2107520     // [48][1228][16]
#define WS_KH    3050624
#define WS_VH    3993728
#define WS_CTX   4936832     // [1228][12][64]  (ends 5879936 floats = 23.5 MB)

// ---- K12: fused k1(precomp) + k2(cheb proj) + k2c(emb_x flat) -------------
__global__ __launch_bounds__(320) void k12_fused(
    const float* __restrict__ x, const float* __restrict__ cheb,
    const float* __restrict__ theta, const float* __restrict__ Wex,
    const float* __restrict__ bex, const float* __restrict__ Weos,
    const float* __restrict__ beos, const float* __restrict__ W_rc,
    const float* __restrict__ W_out, float* __restrict__ ws) {
  int blk = blockIdx.x;
  int tid = threadIdx.x;
  if (blk < 144) {
    int k = blk / BSC, bs = blk % BSC;
    __shared__ float xl[921];
    for (int i = tid; i < 921; i += 320) xl[i] = x[bs * 921 + i];
    __syncthreads();
    int m = tid;
    if (m < NN) {
      const float* ch = cheb + (k * NN + m) * NN;
      float a0 = 0.f, a1 = 0.f, a2 = 0.f, ar = 0.f;
      for (int n = 0; n < NN; ++n) {
        float c = ch[n];
        ar += c;
        a0 = fmaf(c, xl[3 * n], a0);
        a1 = fmaf(c, xl[3 * n + 1], a1);
        a2 = fmaf(c, xl[3 * n + 2], a2);
      }
      ws[WS_CX + ((k * 3 + 0) * BSC + bs) * NN + m] = a0;
      ws[WS_CX + ((k * 3 + 1) * BSC + bs) * NN + m] = a1;
      ws[WS_CX + ((k * 3 + 2) * BSC + bs) * NN + m] = a2;
      if (bs == 0) ws[WS_CROW + k * NN + m] = ar;
    }
  } else if (blk < 3092) {
    int idx = (blk - 144) * 320 + tid;
    if (idx < 943104) {
      int n = idx % NN;
      int t = idx / NN;
      int e = t & 63;
      int bs = t >> 6;
      ws[WS_XFL + idx] = fmaf(x[(bs * NN + n) * 3], Wex[e], bex[e]);
    }
  } else {
    if (tid < 192) {
      int k = tid / 64, d = tid % 64;
      float a0 = 0.f, a1 = 0.f, a2 = 0.f, a3 = 0.f, a4 = 0.f;
      for (int c = 0; c < 64; ++c) {
        float th = theta[(k * 64 + c) * 64 + d];
        a0 = fmaf(Wex[c], th, a0);
        a1 = fmaf(bex[c], th, a1);
        a2 = fmaf(Weos[c], th, a2);
        a3 = fmaf(Weos[64 + c], th, a3);
        a4 = fmaf(beos[c], th, a4);
      }
      ws[WS_TXD + tid] = a0; ws[WS_TBD + tid] = a1; ws[WS_T1D + tid] = a2;
      ws[WS_T2D + tid] = a3; ws[WS_TOB + tid] = a4;
    }
    for (int i = tid; i < 4096; i += 320) {
      int hh = i >> 6, f = i & 63;
      ws[WS_WRCT + i] = W_rc[f * 64 + hh];
      ws[WS_WOT + i]  = W_out[f * 64 + hh];
    }
  }
}

// ---- KB: k3 scan (blocks 0..1227, R11 known-good body) + k5kv (K/V proj,
// blocks 1228..4923) fused in one grid. K/V depends only on XFL (k12), so
// those blocks soak the issue slots the barrier-bound scan leaves idle.
__global__ __launch_bounds__(384) void kB_scan_kv(
    const float* __restrict__ U_x, const float* __restrict__ V_x,
    const float* __restrict__ b_x, const float* __restrict__ U_g,
    const float* __restrict__ V_g, const float* __restrict__ b_g,
    const float* __restrict__ W_ff1, const float* __restrict__ b_ff1,
    const float* __restrict__ W_ff2, const float* __restrict__ b_ff2,
    const float* __restrict__ W_tc, const float* __restrict__ b_tc,
    const float* __restrict__ W_in, const float* __restrict__ b_in,
    float* __restrict__ ws) {
  __shared__ float sh[2688];
  int blk = blockIdx.x;
  int tid = threadIdx.x;

  if (blk >= 1228) {
    // ---------------- k5kv: K/V projections from XFL windows ----------------
    int bb = blk - 1228;
    int g = bb / 77, mt = bb % 77;
    int s = g >> 2, a = g & 3;
    int m0 = mt * 16;
    float* xw = sh;                       // [16][64]
    for (int i = tid; i < 1024; i += 384) {
      int mi = i >> 6, e = i & 63;
      int m = m0 + mi;
      if (m < LL) xw[i] = ws[WS_XFL + m * 768 + s * 64 + e];
    }
    __syncthreads();
    if (tid < 256) {
      int mi = tid >> 4, d = tid & 15;
      int m = m0 + mi;
      if (m < LL) {
        int f = a * 16 + d;
        float ak = b_in[64 + f], av = b_in[128 + f];
        const float* xr = &xw[mi * 64];
        for (int e = 0; e < 64; ++e) {
          ak = fmaf(xr[e], W_in[(64 + f) * 64 + e], ak);
          av = fmaf(xr[e], W_in[(128 + f) * 64 + e], av);
        }
        int o = (g * LL + m) * 16 + d;
        ws[WS_KH + o] = ak; ws[WS_VH + o] = av;
      }
    }
    return;
  }

  // ---------------- k3: gcn + U-proj + LSTM scan + FF + tc_last ------------
  float* gcx = sh;             // [768]
  float* gcos = sh + 768;      // [768]
  float* hsb = sh + 1536;      // [768]
  float* sg = sh + 2304;       // [256]
  float* sv = sh + 2560;       // [128]
  int l = blk;
  int b = l / NN, n = l % NN;

  for (int idx = tid; idx < 768; idx += 384) {
    int s = idx >> 6, d = idx & 63;
    int bs = b * SS + s;
    float ax = 0.f, ao = 0.f;
#pragma unroll
    for (int k = 0; k < 3; ++k) {
      float c0 = ws[WS_CX + ((k * 3 + 0) * BSC + bs) * NN + n];
      float c1 = ws[WS_CX + ((k * 3 + 1) * BSC + bs) * NN + n];
      float c2 = ws[WS_CX + ((k * 3 + 2) * BSC + bs) * NN + n];
      float cr = ws[WS_CROW + k * NN + n];
      ax += c0 * ws[WS_TXD + k * 64 + d] + cr * ws[WS_TBD + k * 64 + d];
      ao += c1 * ws[WS_T1D + k * 64 + d] + c2 * ws[WS_T2D + k * 64 + d] +
            cr * ws[WS_TOB + k * 64 + d];
    }
    gcx[idx] = fmaxf(ax, 0.f);
    gcos[idx] = fmaxf(ao, 0.f);
  }
  __syncthreads();

  float gr[12];
  float vcol[64];
  if (tid < 256) {
#pragma unroll
    for (int s = 0; s < 12; ++s) gr[s] = b_x[tid];
    for (int c4 = 0; c4 < 16; ++c4) {
      float u0 = U_x[(4 * c4 + 0) * 256 + tid];
      float u1 = U_x[(4 * c4 + 1) * 256 + tid];
      float u2 = U_x[(4 * c4 + 2) * 256 + tid];
      float u3 = U_x[(4 * c4 + 3) * 256 + tid];
#pragma unroll
      for (int s = 0; s < 12; ++s) {
        float4 g = *reinterpret_cast<const float4*>(&gcx[s * 64 + 4 * c4]);
        gr[s] = fmaf(g.x, u0, fmaf(g.y, u1, fmaf(g.z, u2, fmaf(g.w, u3, gr[s]))));
      }
    }
#pragma unroll
    for (int c = 0; c < 64; ++c) vcol[c] = V_x[c * 256 + tid];
  } else {
    int j2 = tid - 256;
#pragma unroll
    for (int s = 0; s < 12; ++s) gr[s] = b_g[j2];
    for (int c4 = 0; c4 < 16; ++c4) {
      float u0 = U_g[(4 * c4 + 0) * 128 + j2];
      float u1 = U_g[(4 * c4 + 1) * 128 + j2];
      float u2 = U_g[(4 * c4 + 2) * 128 + j2];
      float u3 = U_g[(4 * c4 + 3) * 128 + j2];
#pragma unroll
      for (int s = 0; s < 12; ++s) {
        float4 g = *reinterpret_cast<const float4*>(&gcos[s * 64 + 4 * c4]);
        gr[s] = fmaf(g.x, u0, fmaf(g.y, u1, fmaf(g.z, u2, fmaf(g.w, u3, gr[s]))));
      }
    }
#pragma unroll
    for (int c = 0; c < 64; ++c) vcol[c] = V_g[c * 128 + j2];
  }

  float ct = 0.f;
  for (int s = 0; s < 12; ++s) {
    float a = gr[s];
    if (s > 0) {
      const float* hp = &hsb[(s - 1) * 64];
      float a0 = 0.f, a1 = 0.f, a2 = 0.f, a3 = 0.f;
#pragma unroll
      for (int c4 = 0; c4 < 16; c4 += 4) {
        float4 h0 = *reinterpret_cast<const float4*>(&hp[4 * c4]);
        float4 h1 = *reinterpret_cast<const float4*>(&hp[4 * c4 + 4]);
        float4 h2 = *reinterpret_cast<const float4*>(&hp[4 * c4 + 8]);
        float4 h3 = *reinterpret_cast<const float4*>(&hp[4 * c4 + 12]);
        a0 = fmaf(h0.x, vcol[4 * c4 + 0], fmaf(h0.y, vcol[4 * c4 + 1],
             fmaf(h0.z, vcol[4 * c4 + 2], fmaf(h0.w, vcol[4 * c4 + 3], a0))));
        a1 = fmaf(h1.x, vcol[4 * c4 + 4], fmaf(h1.y, vcol[4 * c4 + 5],
             fmaf(h1.z, vcol[4 * c4 + 6], fmaf(h1.w, vcol[4 * c4 + 7], a1))));
        a2 = fmaf(h2.x, vcol[4 * c4 + 8], fmaf(h2.y, vcol[4 * c4 + 9],
             fmaf(h2.z, vcol[4 * c4 + 10], fmaf(h2.w, vcol[4 * c4 + 11], a2))));
        a3 = fmaf(h3.x, vcol[4 * c4 + 12], fmaf(h3.y, vcol[4 * c4 + 13],
             fmaf(h3.z, vcol[4 * c4 + 14], fmaf(h3.w, vcol[4 * c4 + 15], a3))));
      }
      a += (a0 + a1) + (a2 + a3);
    }
    float sig = 1.f / (1.f + __expf(-a));
    if (tid < 256) sg[tid] = sig; else sv[tid - 256] = sig;
    __syncthreads();
    if (tid < 64) {
      ct = sv[tid] * sg[tid] * ct + sv[64 + tid] * sg[64 + tid] * sg[192 + tid];
      hsb[s * 64 + tid] = sg[128 + tid] * tanhf(ct);
    }
    __syncthreads();
  }

  for (int idx = tid; idx < 768; idx += 384) {
    int s = idx >> 6, d = idx & 63;
    float acc = b_ff1[d];
    for (int c4 = 0; c4 < 16; ++c4) {
      float4 h4 = *reinterpret_cast<const float4*>(&hsb[s * 64 + 4 * c4]);
      acc = fmaf(h4.x, W_ff1[(4 * c4 + 0) * 64 + d],
            fmaf(h4.y, W_ff1[(4 * c4 + 1) * 64 + d],
            fmaf(h4.z, W_ff1[(4 * c4 + 2) * 64 + d],
            fmaf(h4.w, W_ff1[(4 * c4 + 3) * 64 + d], acc))));
    }
    gcx[idx] = fmaxf(acc, 0.f);
  }
  __syncthreads();
  for (int idx = tid; idx < 768; idx += 384) {
    int s = idx >> 6, h = idx & 63;
    float acc = b_ff2[h];
    for (int c4 = 0; c4 < 16; ++c4) {
      float4 t4 = *reinterpret_cast<const float4*>(&gcx[s * 64 + 4 * c4]);
      acc = fmaf(t4.x, W_ff2[(4 * c4 + 0) * 64 + h],
            fmaf(t4.y, W_ff2[(4 * c4 + 1) * 64 + h],
            fmaf(t4.z, W_ff2[(4 * c4 + 2) * 64 + h],
            fmaf(t4.w, W_ff2[(4 * c4 + 3) * 64 + h], acc))));
    }
    ws[WS_H2 + ((b * SS + s) * NN + n) * 64 + h] = acc;
    gcos[idx] = acc;
  }
  __syncthreads();
  if (tid < 64) {
    int f = tid;
    float acc = b_tc[f];
    for (int h = 0; h < 64; ++h) {
      acc = fmaf(gcos[10 * 64 + h], W_tc[(f * 64 + h) * 3 + 0], acc);
      acc = fmaf(gcos[11 * 64 + h], W_tc[(f * 64 + h) * 3 + 1], acc);
    }
    ws[WS_TFL + (b * 64 + f) * NN + n] = acc;
  }
}

// ---- K5q: q projection only (reads TFL windows, writes QH) ----------------
__global__ __launch_bounds__(256) void k5q(const float* __restrict__ W_in,
                                           const float* __restrict__ b_in,
                                           float* __restrict__ ws) {
  int blk = blockIdx.x;
  int g = blk / 77, mt = blk % 77;
  int s = g >> 2, a = g & 3;
  int m0 = mt * 16;
  __shared__ float qw[1024];
  for (int i = threadIdx.x; i < 1024; i += 256) {
    int mi = i >> 6, e = i & 63;
    int m = m0 + mi;
    if (m < LL) {
      int base = m * 768 + s * 64;
      int bq = base / 235776;
      int off = base % 19648;
      qw[i] = ws[WS_TFL + bq * 19648 + off + e];
    }
  }
  __syncthreads();
  int mi = threadIdx.x >> 4, d = threadIdx.x & 15;
  int m = m0 + mi;
  if (m < LL) {
    int f = a * 16 + d;
    float aq = b_in[f];
    const float* qr = &qw[mi * 64];
    for (int e = 0; e < 64; ++e) aq = fmaf(qr[e], W_in[f * 64 + e], aq);
    ws[WS_QH + (g * LL + m) * 16 + d] = aq;
  }
}

// ---- K6: flash attention — LDS tiles + split-K, 2 queries per lane --------
__global__ __launch_bounds__(512) void k6_attn(float* __restrict__ ws) {
  int blk = blockIdx.x;
  int g = blk / 10, qt = blk % 10;
  int s = g >> 2, a = g & 3;
  int tid = threadIdx.x;
  int w = tid >> 6;
  int qi = tid & 63;
  int l0 = qt * 128 + qi;
  int l1 = l0 + 64;
  bool act0 = (l0 < LL), act1 = (l1 < LL);

  __shared__ float sh[9728];
  float4* kt4 = reinterpret_cast<float4*>(sh);
  float4* vt4 = reinterpret_cast<float4*>(sh + 4096);

  float q0[16], q1[16], cx0[16], cx1[16];
  if (act0) {
    const float4* qp = reinterpret_cast<const float4*>(ws + WS_QH + (g * LL + l0) * 16);
#pragma unroll
    for (int jj = 0; jj < 4; ++jj) {
      float4 t = qp[jj];
      q0[4 * jj] = t.x * 0.25f; q0[4 * jj + 1] = t.y * 0.25f;
      q0[4 * jj + 2] = t.z * 0.25f; q0[4 * jj + 3] = t.w * 0.25f;
    }
  } else {
#pragma unroll
    for (int d = 0; d < 16; ++d) q0[d] = 0.f;
  }
  if (act1) {
    const float4* qp = reinterpret_cast<const float4*>(ws + WS_QH + (g * LL + l1) * 16);
#pragma unroll
    for (int jj = 0; jj < 4; ++jj) {
      float4 t = qp[jj];
      q1[4 * jj] = t.x * 0.25f; q1[4 * jj + 1] = t.y * 0.25f;
      q1[4 * jj + 2] = t.z * 0.25f; q1[4 * jj + 3] = t.w * 0.25f;
    }
  } else {
#pragma unroll
    for (int d = 0; d < 16; ++d) q1[d] = 0.f;
  }
#pragma unroll
  for (int d = 0; d < 16; ++d) { cx0[d] = 0.f; cx1[d] = 0.f; }
  float den0 = 0.f, den1 = 0.f;

  const float4* kb = reinterpret_cast<const float4*>(ws + WS_KH + g * LL * 16);
  const float4* vb = reinterpret_cast<const float4*>(ws + WS_VH + g * LL * 16);

  for (int mt = 0; mt < 5; ++mt) {
    int mbase = mt * 256;
    int cnt = LL - mbase; if (cnt > 256) cnt = 256;
    int nf4 = cnt * 4;
    for (int i = tid; i < nf4; i += 512) {
      kt4[i] = kb[mbase * 4 + i];
      vt4[i] = vb[mbase * 4 + i];
    }
    __syncthreads();
    int e0 = w * 32;
    int e1 = e0 + 32; if (e1 > cnt) e1 = cnt;
    for (int mi = e0; mi < e1; ++mi) {
      float4 ka = kt4[mi * 4], kbb = kt4[mi * 4 + 1];
      float4 kc = kt4[mi * 4 + 2], kd = kt4[mi * 4 + 3];
      float p0 = q0[0] * ka.x, p1 = q1[0] * ka.x;
      p0 = fmaf(q0[1], ka.y, p0);   p1 = fmaf(q1[1], ka.y, p1);
      p0 = fmaf(q0[2], ka.z, p0);   p1 = fmaf(q1[2], ka.z, p1);
      p0 = fmaf(q0[3], ka.w, p0);   p1 = fmaf(q1[3], ka.w, p1);
      p0 = fmaf(q0[4], kbb.x, p0);  p1 = fmaf(q1[4], kbb.x, p1);
      p0 = fmaf(q0[5], kbb.y, p0);  p1 = fmaf(q1[5], kbb.y, p1);
      p0 = fmaf(q0[6], kbb.z, p0);  p1 = fmaf(q1[6], kbb.z, p1);
      p0 = fmaf(q0[7], kbb.w, p0);  p1 = fmaf(q1[7], kbb.w, p1);
      p0 = fmaf(q0[8], kc.x, p0);   p1 = fmaf(q1[8], kc.x, p1);
      p0 = fmaf(q0[9], kc.y, p0);   p1 = fmaf(q1[9], kc.y, p1);
      p0 = fmaf(q0[10], kc.z, p0);  p1 = fmaf(q1[10], kc.z, p1);
      p0 = fmaf(q0[11], kc.w, p0);  p1 = fmaf(q1[11], kc.w, p1);
      p0 = fmaf(q0[12], kd.x, p0);  p1 = fmaf(q1[12], kd.x, p1);
      p0 = fmaf(q0[13], kd.y, p0);  p1 = fmaf(q1[13], kd.y, p1);
      p0 = fmaf(q0[14], kd.z, p0);  p1 = fmaf(q1[14], kd.z, p1);
      p0 = fmaf(q0[15], kd.w, p0);  p1 = fmaf(q1[15], kd.w, p1);
      float e0w = __expf(fminf(p0, 60.f));
      float e1w = __expf(fminf(p1, 60.f));
      den0 += e0w; den1 += e1w;
      float4 va = vt4[mi * 4], vbb = vt4[mi * 4 + 1];
      float4 vc = vt4[mi * 4 + 2], vd = vt4[mi * 4 + 3];
      cx0[0]  = fmaf(e0w, va.x, cx0[0]);   cx1[0]  = fmaf(e1w, va.x, cx1[0]);
      cx0[1]  = fmaf(e0w, va.y, cx0[1]);   cx1[1]  = fmaf(e1w, va.y, cx1[1]);
      cx0[2]  = fmaf(e0w, va.z, cx0[2]);   cx1[2]  = fmaf(e1w, va.z, cx1[2]);
      cx0[3]  = fmaf(e0w, va.w, cx0[3]);   cx1[3]  = fmaf(e1w, va.w, cx1[3]);
      cx0[4]  = fmaf(e0w, vbb.x, cx0[4]);  cx1[4]  = fmaf(e1w, vbb.x, cx1[4]);
      cx0[5]  = fmaf(e0w, vbb.y, cx0[5]);  cx1[5]  = fmaf(e1w, vbb.y, cx1[5]);
      cx0[6]  = fmaf(e0w, vbb.z, cx0[6]);  cx1[6]  = fmaf(e1w, vbb.z, cx1[6]);
      cx0[7]  = fmaf(e0w, vbb.w, cx0[7]);  cx1[7]  = fmaf(e1w, vbb.w, cx1[7]);
      cx0[8]  = fmaf(e0w, vc.x, cx0[8]);   cx1[8]  = fmaf(e1w, vc.x, cx1[8]);
      cx0[9]  = fmaf(e0w, vc.y, cx0[9]);   cx1[9]  = fmaf(e1w, vc.y, cx1[9]);
      cx0[10] = fmaf(e0w, vc.z, cx0[10]);  cx1[10] = fmaf(e1w, vc.z, cx1[10]);
      cx0[11] = fmaf(e0w, vc.w, cx0[11]);  cx1[11] = fmaf(e1w, vc.w, cx1[11]);
      cx0[12] = fmaf(e0w, vd.x, cx0[12]);  cx1[12] = fmaf(e1w, vd.x, cx1[12]);
      cx0[13] = fmaf(e0w, vd.y, cx0[13]);  cx1[13] = fmaf(e1w, vd.y, cx1[13]);
      cx0[14] = fmaf(e0w, vd.z, cx0[14]);  cx1[14] = fmaf(e1w, vd.z, cx1[14]);
      cx0[15] = fmaf(e0w, vd.w, cx0[15]);  cx1[15] = fmaf(e1w, vd.w, cx1[15]);
    }
    __syncthreads();
  }

  float* sden = sh;
  float* scx  = sh + 512;
#pragma unroll
  for (int ph = 0; ph < 2; ++ph) {
    sden[w * 64 + qi] = ph ? den1 : den0;
    const float* cxp = ph ? cx1 : cx0;
#pragma unroll
    for (int d = 0; d < 16; ++d) scx[(w * 64 + qi) * 17 + d] = cxp[d];
    __syncthreads();
    if (tid < 256) {
      int q2 = tid >> 2, jj = tid & 3;
      int l2 = qt * 128 + ph * 64 + q2;
      if (l2 < LL) {
        float dtot = 0.f, c0 = 0.f, c1 = 0.f, c2 = 0.f, c3 = 0.f;
#pragma unroll
        for (int u = 0; u < 8; ++u) {
          dtot += sden[u * 64 + q2];
          const float* cp = &scx[(u * 64 + q2) * 17 + jj * 4];
          c0 += cp[0]; c1 += cp[1]; c2 += cp[2]; c3 += cp[3];
        }
        float inv = 1.f / dtot;
        float* op = ws + WS_CTX + (l2 * SS + s) * 64 + a * 16 + jj * 4;
        *reinterpret_cast<float4*>(op) =
            make_float4(c0 * inv, c1 * inv, c2 * inv, c3 * inv);
      }
    }
    __syncthreads();
  }
}

// ---- K7a: out-proj + FFA + residual conv, one block per (l,s) -------------
__global__ __launch_bounds__(64) void k7a_comb(
    const float* __restrict__ W_fa1, const float* __restrict__ b_fa1,
    const float* __restrict__ W_fa2, const float* __restrict__ b_fa2,
    const float* __restrict__ b_rc, const float* __restrict__ b_out,
    float* __restrict__ ws) {
  int blk = blockIdx.x;
  int l = blk / SS, s = blk % SS;
  int b = l / NN, n = l % NN;
  int f = threadIdx.x;
  __shared__ float h2r[64], ctr[64], dsrL[64], trL[64];

  h2r[f] = ws[WS_H2 + ((b * SS + s) * NN + n) * 64 + f];
  ctr[f] = ws[WS_CTX + (l * SS + s) * 64 + f];
  __syncthreads();

  float dsr = b_out[f], res = b_rc[f];
  for (int q = 0; q < 64; ++q) {
    dsr = fmaf(ctr[q], ws[WS_WOT + q * 64 + f], dsr);
    res = fmaf(h2r[q], ws[WS_WRCT + q * 64 + f], res);
  }
  dsrL[f] = dsr;
  __syncthreads();

  float t = b_fa1[f];
  for (int q = 0; q < 64; ++q) t = fmaf(dsrL[q], W_fa1[q * 64 + f], t);
  trL[f] = fmaxf(t, 0.f);
  __syncthreads();

  float ff = b_fa2[f];
  for (int q = 0; q < 64; ++q) ff = fmaf(trL[q], W_fa2[q * 64 + f], ff);
  ws[WS_XFL + (l * SS + s) * 64 + f] = res + ff;
}

// ---- K7b: final conv — out[b,p,n] = sum_{s,q} comb[l][s][q]*W_fin[p][s][q] -
__global__ __launch_bounds__(320) void k7b_fin(
    const float* __restrict__ W_fin, const float* __restrict__ b_fin,
    const float* __restrict__ ws, float* __restrict__ out) {
  int blk = blockIdx.x;
  int b = blk / SS, p = blk % SS;
  int tid = threadIdx.x;
  __shared__ float wf[768];
  for (int i = tid; i < 768; i += 320) wf[i] = W_fin[p * 768 + i];
  __syncthreads();
  int n = tid;
  if (n < NN) {
    const float* cb = ws + WS_XFL + (b * NN + n) * 768;
    float a0 = 0.f, a1 = 0.f, a2 = 0.f, a3 = 0.f;
    for (int i = 0; i < 768; i += 4) {
      a0 = fmaf(cb[i], wf[i], a0);
      a1 = fmaf(cb[i + 1], wf[i + 1], a1);
      a2 = fmaf(cb[i + 2], wf[i + 2], a2);
      a3 = fmaf(cb[i + 3], wf[i + 3], a3);
    }
    out[(b * SS + p) * NN + n] = (a0 + a1) + (a2 + a3) + b_fin[p];
  }
}

extern "C" void kernel_launch(void* const* d_in, const int* in_sizes, int n_in,
                              void* d_out, int out_size, void* d_ws, size_t ws_size,
                              hipStream_t stream) {
  (void)in_sizes; (void)n_in; (void)out_size; (void)ws_size;
  const float* x     = (const float*)d_in[0];
  const float* cheb  = (const float*)d_in[1];
  const float* theta = (const float*)d_in[2];
  const float* Wex   = (const float*)d_in[3];
  const float* bex   = (const float*)d_in[4];
  const float* Weos  = (const float*)d_in[5];
  const float* beos  = (const float*)d_in[6];
  const float* U_x   = (const float*)d_in[7];
  const float* V_x   = (const float*)d_in[8];
  const float* b_x   = (const float*)d_in[9];
  const float* U_g   = (const float*)d_in[10];
  const float* V_g   = (const float*)d_in[11];
  const float* b_g   = (const float*)d_in[12];
  const float* W_ff1 = (const float*)d_in[13];
  const float* b_ff1 = (const float*)d_in[14];
  const float* W_ff2 = (const float*)d_in[15];
  const float* b_ff2 = (const float*)d_in[16];
  const float* W_tc  = (const float*)d_in[17];
  const float* b_tc  = (const float*)d_in[18];
  const float* W_rc  = (const float*)d_in[19];
  const float* b_rc  = (const float*)d_in[20];
  const float* W_in  = (const float*)d_in[21];
  const float* b_in  = (const float*)d_in[22];
  const float* W_out = (const float*)d_in[23];
  const float* b_out = (const float*)d_in[24];
  const float* W_fa1 = (const float*)d_in[25];
  const float* b_fa1 = (const float*)d_in[26];
  const float* W_fa2 = (const float*)d_in[27];
  const float* b_fa2 = (const float*)d_in[28];
  const float* W_fin = (const float*)d_in[29];
  const float* b_fin = (const float*)d_in[30];
  float* ws = (float*)d_ws;
  float* outp = (float*)d_out;

  k12_fused<<<3093, 320, 0, stream>>>(x, cheb, theta, Wex, bex, Weos, beos,
                                      W_rc, W_out, ws);
  kB_scan_kv<<<1228 + 3696, 384, 0, stream>>>(U_x, V_x, b_x, U_g, V_g, b_g,
                                              W_ff1, b_ff1, W_ff2, b_ff2,
                                              W_tc, b_tc, W_in, b_in, ws);
  k5q<<<3696, 256, 0, stream>>>(W_in, b_in, ws);
  k6_attn<<<480, 512, 0, stream>>>(ws);
  k7a_comb<<<LL * SS, 64, 0, stream>>>(W_fa1, b_fa1, W_fa2, b_fa2,
                                       b_rc, b_out, ws);
  k7b_fin<<<BB * SS, 320, 0, stream>>>(W_fin, b_fin, ws, outp);
}

// Round 15
// 352.635 us; speedup vs baseline: 1.0423x; 1.0423x over previous
//
#include <hip/hip_runtime.h>
#include <hip/hip_bf16.h>

// Problem constants
#define BB 4
#define SS 12
#define NN 307
#define LL 1228      // B*N
#define BSC 48       // B*S
#define GG 48        // S*HEADS
// Workspace offsets (floats)
#define WS_CX    0           // [3][3][48][307] = 132624
#define WS_CROW  132624      // [3][307]
#define WS_TXD   133568      // [3][64]
#define WS_TBD   133760
#define WS_T1D   133952
#define WS_T2D   134144
#define WS_TOB   134336
#define WS_WRCT  134528      // [64][64] W_rc transposed
#define WS_WOT   138624      // [64][64] W_out transposed
#define WS_H2    142720      // [B][S][N][64] post-FF hidden = 943104
#define WS_TFL   1085824     // [B][64][307] tc_last in (b,f,n) order = 78592
#define WS_XFL   1164416     // [B][S][64][307] emb_x; REUSED by k7a as comb[L][S][64]
#define WS_QH    2107520     // [48][1228][16]
#define WS_KH    3050624
#define WS_VH    3993728
#define WS_CTX   4936832     // [1228][12][64]  (ends 5879936 floats = 23.5 MB)

// ---- K12: fused k1(precomp) + k2(cheb proj) + k2c(emb_x flat) -------------
__global__ __launch_bounds__(320) void k12_fused(
    const float* __restrict__ x, const float* __restrict__ cheb,
    const float* __restrict__ theta, const float* __restrict__ Wex,
    const float* __restrict__ bex, const float* __restrict__ Weos,
    const float* __restrict__ beos, const float* __restrict__ W_rc,
    const float* __restrict__ W_out, float* __restrict__ ws) {
  int blk = blockIdx.x;
  int tid = threadIdx.x;
  if (blk < 144) {
    int k = blk / BSC, bs = blk % BSC;
    __shared__ float xl[921];
    for (int i = tid; i < 921; i += 320) xl[i] = x[bs * 921 + i];
    __syncthreads();
    int m = tid;
    if (m < NN) {
      const float* ch = cheb + (k * NN + m) * NN;
      float a0 = 0.f, a1 = 0.f, a2 = 0.f, ar = 0.f;
      for (int n = 0; n < NN; ++n) {
        float c = ch[n];
        ar += c;
        a0 = fmaf(c, xl[3 * n], a0);
        a1 = fmaf(c, xl[3 * n + 1], a1);
        a2 = fmaf(c, xl[3 * n + 2], a2);
      }
      ws[WS_CX + ((k * 3 + 0) * BSC + bs) * NN + m] = a0;
      ws[WS_CX + ((k * 3 + 1) * BSC + bs) * NN + m] = a1;
      ws[WS_CX + ((k * 3 + 2) * BSC + bs) * NN + m] = a2;
      if (bs == 0) ws[WS_CROW + k * NN + m] = ar;
    }
  } else if (blk < 3092) {
    int idx = (blk - 144) * 320 + tid;
    if (idx < 943104) {
      int n = idx % NN;
      int t = idx / NN;
      int e = t & 63;
      int bs = t >> 6;
      ws[WS_XFL + idx] = fmaf(x[(bs * NN + n) * 3], Wex[e], bex[e]);
    }
  } else {
    if (tid < 192) {
      int k = tid / 64, d = tid % 64;
      float a0 = 0.f, a1 = 0.f, a2 = 0.f, a3 = 0.f, a4 = 0.f;
      for (int c = 0; c < 64; ++c) {
        float th = theta[(k * 64 + c) * 64 + d];
        a0 = fmaf(Wex[c], th, a0);
        a1 = fmaf(bex[c], th, a1);
        a2 = fmaf(Weos[c], th, a2);
        a3 = fmaf(Weos[64 + c], th, a3);
        a4 = fmaf(beos[c], th, a4);
      }
      ws[WS_TXD + tid] = a0; ws[WS_TBD + tid] = a1; ws[WS_T1D + tid] = a2;
      ws[WS_T2D + tid] = a3; ws[WS_TOB + tid] = a4;
    }
    for (int i = tid; i < 4096; i += 320) {
      int hh = i >> 6, f = i & 63;
      ws[WS_WRCT + i] = W_rc[f * 64 + hh];
      ws[WS_WOT + i]  = W_out[f * 64 + hh];
    }
  }
}

// ---- K3: fused gcn + U-proj + LSTM scan + FF + tc_last (R11 known-good) ---
__global__ __launch_bounds__(384) void k3_scan(
    const float* __restrict__ U_x, const float* __restrict__ V_x,
    const float* __restrict__ b_x, const float* __restrict__ U_g,
    const float* __restrict__ V_g, const float* __restrict__ b_g,
    const float* __restrict__ W_ff1, const float* __restrict__ b_ff1,
    const float* __restrict__ W_ff2, const float* __restrict__ b_ff2,
    const float* __restrict__ W_tc, const float* __restrict__ b_tc,
    float* __restrict__ ws) {
  int l = blockIdx.x;
  int b = l / NN, n = l % NN;
  int tid = threadIdx.x;
  __shared__ float gcx[768], gcos[768], hsb[768], sg[256], sv[128];

  for (int idx = tid; idx < 768; idx += 384) {
    int s = idx >> 6, d = idx & 63;
    int bs = b * SS + s;
    float ax = 0.f, ao = 0.f;
#pragma unroll
    for (int k = 0; k < 3; ++k) {
      float c0 = ws[WS_CX + ((k * 3 + 0) * BSC + bs) * NN + n];
      float c1 = ws[WS_CX + ((k * 3 + 1) * BSC + bs) * NN + n];
      float c2 = ws[WS_CX + ((k * 3 + 2) * BSC + bs) * NN + n];
      float cr = ws[WS_CROW + k * NN + n];
      ax += c0 * ws[WS_TXD + k * 64 + d] + cr * ws[WS_TBD + k * 64 + d];
      ao += c1 * ws[WS_T1D + k * 64 + d] + c2 * ws[WS_T2D + k * 64 + d] +
            cr * ws[WS_TOB + k * 64 + d];
    }
    gcx[idx] = fmaxf(ax, 0.f);
    gcos[idx] = fmaxf(ao, 0.f);
  }
  __syncthreads();

  float gr[12];
  float vcol[64];
  if (tid < 256) {
#pragma unroll
    for (int s = 0; s < 12; ++s) gr[s] = b_x[tid];
    for (int c4 = 0; c4 < 16; ++c4) {
      float u0 = U_x[(4 * c4 + 0) * 256 + tid];
      float u1 = U_x[(4 * c4 + 1) * 256 + tid];
      float u2 = U_x[(4 * c4 + 2) * 256 + tid];
      float u3 = U_x[(4 * c4 + 3) * 256 + tid];
#pragma unroll
      for (int s = 0; s < 12; ++s) {
        float4 g = *reinterpret_cast<const float4*>(&gcx[s * 64 + 4 * c4]);
        gr[s] = fmaf(g.x, u0, fmaf(g.y, u1, fmaf(g.z, u2, fmaf(g.w, u3, gr[s]))));
      }
    }
#pragma unroll
    for (int c = 0; c < 64; ++c) vcol[c] = V_x[c * 256 + tid];
  } else {
    int j2 = tid - 256;
#pragma unroll
    for (int s = 0; s < 12; ++s) gr[s] = b_g[j2];
    for (int c4 = 0; c4 < 16; ++c4) {
      float u0 = U_g[(4 * c4 + 0) * 128 + j2];
      float u1 = U_g[(4 * c4 + 1) * 128 + j2];
      float u2 = U_g[(4 * c4 + 2) * 128 + j2];
      float u3 = U_g[(4 * c4 + 3) * 128 + j2];
#pragma unroll
      for (int s = 0; s < 12; ++s) {
        float4 g = *reinterpret_cast<const float4*>(&gcos[s * 64 + 4 * c4]);
        gr[s] = fmaf(g.x, u0, fmaf(g.y, u1, fmaf(g.z, u2, fmaf(g.w, u3, gr[s]))));
      }
    }
#pragma unroll
    for (int c = 0; c < 64; ++c) vcol[c] = V_g[c * 128 + j2];
  }

  float ct = 0.f;
  for (int s = 0; s < 12; ++s) {
    float a = gr[s];
    if (s > 0) {
      const float* hp = &hsb[(s - 1) * 64];
      float a0 = 0.f, a1 = 0.f, a2 = 0.f, a3 = 0.f;
#pragma unroll
      for (int c4 = 0; c4 < 16; c4 += 4) {
        float4 h0 = *reinterpret_cast<const float4*>(&hp[4 * c4]);
        float4 h1 = *reinterpret_cast<const float4*>(&hp[4 * c4 + 4]);
        float4 h2 = *reinterpret_cast<const float4*>(&hp[4 * c4 + 8]);
        float4 h3 = *reinterpret_cast<const float4*>(&hp[4 * c4 + 12]);
        a0 = fmaf(h0.x, vcol[4 * c4 + 0], fmaf(h0.y, vcol[4 * c4 + 1],
             fmaf(h0.z, vcol[4 * c4 + 2], fmaf(h0.w, vcol[4 * c4 + 3], a0))));
        a1 = fmaf(h1.x, vcol[4 * c4 + 4], fmaf(h1.y, vcol[4 * c4 + 5],
             fmaf(h1.z, vcol[4 * c4 + 6], fmaf(h1.w, vcol[4 * c4 + 7], a1))));
        a2 = fmaf(h2.x, vcol[4 * c4 + 8], fmaf(h2.y, vcol[4 * c4 + 9],
             fmaf(h2.z, vcol[4 * c4 + 10], fmaf(h2.w, vcol[4 * c4 + 11], a2))));
        a3 = fmaf(h3.x, vcol[4 * c4 + 12], fmaf(h3.y, vcol[4 * c4 + 13],
             fmaf(h3.z, vcol[4 * c4 + 14], fmaf(h3.w, vcol[4 * c4 + 15], a3))));
      }
      a += (a0 + a1) + (a2 + a3);
    }
    float sig = 1.f / (1.f + __expf(-a));
    if (tid < 256) sg[tid] = sig; else sv[tid - 256] = sig;
    __syncthreads();
    if (tid < 64) {
      ct = sv[tid] * sg[tid] * ct + sv[64 + tid] * sg[64 + tid] * sg[192 + tid];
      hsb[s * 64 + tid] = sg[128 + tid] * tanhf(ct);
    }
    __syncthreads();
  }

  for (int idx = tid; idx < 768; idx += 384) {
    int s = idx >> 6, d = idx & 63;
    float acc = b_ff1[d];
    for (int c4 = 0; c4 < 16; ++c4) {
      float4 h4 = *reinterpret_cast<const float4*>(&hsb[s * 64 + 4 * c4]);
      acc = fmaf(h4.x, W_ff1[(4 * c4 + 0) * 64 + d],
            fmaf(h4.y, W_ff1[(4 * c4 + 1) * 64 + d],
            fmaf(h4.z, W_ff1[(4 * c4 + 2) * 64 + d],
            fmaf(h4.w, W_ff1[(4 * c4 + 3) * 64 + d], acc))));
    }
    gcx[idx] = fmaxf(acc, 0.f);
  }
  __syncthreads();
  for (int idx = tid; idx < 768; idx += 384) {
    int s = idx >> 6, h = idx & 63;
    float acc = b_ff2[h];
    for (int c4 = 0; c4 < 16; ++c4) {
      float4 t4 = *reinterpret_cast<const float4*>(&gcx[s * 64 + 4 * c4]);
      acc = fmaf(t4.x, W_ff2[(4 * c4 + 0) * 64 + h],
            fmaf(t4.y, W_ff2[(4 * c4 + 1) * 64 + h],
            fmaf(t4.z, W_ff2[(4 * c4 + 2) * 64 + h],
            fmaf(t4.w, W_ff2[(4 * c4 + 3) * 64 + h], acc))));
    }
    ws[WS_H2 + ((b * SS + s) * NN + n) * 64 + h] = acc;
    gcos[idx] = acc;
  }
  __syncthreads();
  if (tid < 64) {
    int f = tid;
    float acc = b_tc[f];
    for (int h = 0; h < 64; ++h) {
      acc = fmaf(gcos[10 * 64 + h], W_tc[(f * 64 + h) * 3 + 0], acc);
      acc = fmaf(gcos[11 * 64 + h], W_tc[(f * 64 + h) * 3 + 1], acc);
    }
    ws[WS_TFL + (b * 64 + f) * NN + n] = acc;
  }
}

// ---- K5: q/k/v projections; LDS tiles padded to stride 68 (bank-conflict-
// free: stride 64 floats put all 4 per-wave mi rows in the same bank) -------
__global__ __launch_bounds__(256) void k5_qkv(const float* __restrict__ W_in,
                                              const float* __restrict__ b_in,
                                              float* __restrict__ ws) {
  int blk = blockIdx.x;
  int g = blk / 77, mt = blk % 77;
  int s = g >> 2, a = g & 3;
  int m0 = mt * 16;
  __shared__ float xw[16][68], qw[16][68];
  for (int i = threadIdx.x; i < 1024; i += 256) {
    int mi = i >> 6, e = i & 63;
    int m = m0 + mi;
    if (m < LL) {
      int base = m * 768 + s * 64;         // 64-aligned; never straddles (b,s) runs
      xw[mi][e] = ws[WS_XFL + base + e];
      int bq = base / 235776;              // 235776 = S*64*307
      int off = base % 19648;              // 19648 = 64*307
      qw[mi][e] = ws[WS_TFL + bq * 19648 + off + e];
    }
  }
  __syncthreads();
  int mi = threadIdx.x >> 4, d = threadIdx.x & 15;
  int m = m0 + mi;
  if (m < LL) {
    int f = a * 16 + d;
    float aq = b_in[f], ak = b_in[64 + f], av = b_in[128 + f];
    for (int e = 0; e < 64; ++e) {
      aq = fmaf(qw[mi][e], W_in[f * 64 + e], aq);
      ak = fmaf(xw[mi][e], W_in[(64 + f) * 64 + e], ak);
      av = fmaf(xw[mi][e], W_in[(128 + f) * 64 + e], av);
    }
    int o = (g * LL + m) * 16 + d;
    ws[WS_QH + o] = aq; ws[WS_KH + o] = ak; ws[WS_VH + o] = av;
  }
}

// ---- K6: flash attention — LDS tiles + split-K, 2 queries per lane --------
__global__ __launch_bounds__(512) void k6_attn(float* __restrict__ ws) {
  int blk = blockIdx.x;
  int g = blk / 10, qt = blk % 10;
  int s = g >> 2, a = g & 3;
  int tid = threadIdx.x;
  int w = tid >> 6;
  int qi = tid & 63;
  int l0 = qt * 128 + qi;
  int l1 = l0 + 64;
  bool act0 = (l0 < LL), act1 = (l1 < LL);

  __shared__ float sh[9728];
  float4* kt4 = reinterpret_cast<float4*>(sh);
  float4* vt4 = reinterpret_cast<float4*>(sh + 4096);

  float q0[16], q1[16], cx0[16], cx1[16];
  if (act0) {
    const float4* qp = reinterpret_cast<const float4*>(ws + WS_QH + (g * LL + l0) * 16);
#pragma unroll
    for (int jj = 0; jj < 4; ++jj) {
      float4 t = qp[jj];
      q0[4 * jj] = t.x * 0.25f; q0[4 * jj + 1] = t.y * 0.25f;
      q0[4 * jj + 2] = t.z * 0.25f; q0[4 * jj + 3] = t.w * 0.25f;
    }
  } else {
#pragma unroll
    for (int d = 0; d < 16; ++d) q0[d] = 0.f;
  }
  if (act1) {
    const float4* qp = reinterpret_cast<const float4*>(ws + WS_QH + (g * LL + l1) * 16);
#pragma unroll
    for (int jj = 0; jj < 4; ++jj) {
      float4 t = qp[jj];
      q1[4 * jj] = t.x * 0.25f; q1[4 * jj + 1] = t.y * 0.25f;
      q1[4 * jj + 2] = t.z * 0.25f; q1[4 * jj + 3] = t.w * 0.25f;
    }
  } else {
#pragma unroll
    for (int d = 0; d < 16; ++d) q1[d] = 0.f;
  }
#pragma unroll
  for (int d = 0; d < 16; ++d) { cx0[d] = 0.f; cx1[d] = 0.f; }
  float den0 = 0.f, den1 = 0.f;

  const float4* kb = reinterpret_cast<const float4*>(ws + WS_KH + g * LL * 16);
  const float4* vb = reinterpret_cast<const float4*>(ws + WS_VH + g * LL * 16);

  for (int mt = 0; mt < 5; ++mt) {
    int mbase = mt * 256;
    int cnt = LL - mbase; if (cnt > 256) cnt = 256;
    int nf4 = cnt * 4;
    for (int i = tid; i < nf4; i += 512) {
      kt4[i] = kb[mbase * 4 + i];
      vt4[i] = vb[mbase * 4 + i];
    }
    __syncthreads();
    int e0 = w * 32;
    int e1 = e0 + 32; if (e1 > cnt) e1 = cnt;
    for (int mi = e0; mi < e1; ++mi) {
      float4 ka = kt4[mi * 4], kbb = kt4[mi * 4 + 1];
      float4 kc = kt4[mi * 4 + 2], kd = kt4[mi * 4 + 3];
      float p0 = q0[0] * ka.x, p1 = q1[0] * ka.x;
      p0 = fmaf(q0[1], ka.y, p0);   p1 = fmaf(q1[1], ka.y, p1);
      p0 = fmaf(q0[2], ka.z, p0);   p1 = fmaf(q1[2], ka.z, p1);
      p0 = fmaf(q0[3], ka.w, p0);   p1 = fmaf(q1[3], ka.w, p1);
      p0 = fmaf(q0[4], kbb.x, p0);  p1 = fmaf(q1[4], kbb.x, p1);
      p0 = fmaf(q0[5], kbb.y, p0);  p1 = fmaf(q1[5], kbb.y, p1);
      p0 = fmaf(q0[6], kbb.z, p0);  p1 = fmaf(q1[6], kbb.z, p1);
      p0 = fmaf(q0[7], kbb.w, p0);  p1 = fmaf(q1[7], kbb.w, p1);
      p0 = fmaf(q0[8], kc.x, p0);   p1 = fmaf(q1[8], kc.x, p1);
      p0 = fmaf(q0[9], kc.y, p0);   p1 = fmaf(q1[9], kc.y, p1);
      p0 = fmaf(q0[10], kc.z, p0);  p1 = fmaf(q1[10], kc.z, p1);
      p0 = fmaf(q0[11], kc.w, p0);  p1 = fmaf(q1[11], kc.w, p1);
      p0 = fmaf(q0[12], kd.x, p0);  p1 = fmaf(q1[12], kd.x, p1);
      p0 = fmaf(q0[13], kd.y, p0);  p1 = fmaf(q1[13], kd.y, p1);
      p0 = fmaf(q0[14], kd.z, p0);  p1 = fmaf(q1[14], kd.z, p1);
      p0 = fmaf(q0[15], kd.w, p0);  p1 = fmaf(q1[15], kd.w, p1);
      float e0w = __expf(fminf(p0, 60.f));
      float e1w = __expf(fminf(p1, 60.f));
      den0 += e0w; den1 += e1w;
      float4 va = vt4[mi * 4], vbb = vt4[mi * 4 + 1];
      float4 vc = vt4[mi * 4 + 2], vd = vt4[mi * 4 + 3];
      cx0[0]  = fmaf(e0w, va.x, cx0[0]);   cx1[0]  = fmaf(e1w, va.x, cx1[0]);
      cx0[1]  = fmaf(e0w, va.y, cx0[1]);   cx1[1]  = fmaf(e1w, va.y, cx1[1]);
      cx0[2]  = fmaf(e0w, va.z, cx0[2]);   cx1[2]  = fmaf(e1w, va.z, cx1[2]);
      cx0[3]  = fmaf(e0w, va.w, cx0[3]);   cx1[3]  = fmaf(e1w, va.w, cx1[3]);
      cx0[4]  = fmaf(e0w, vbb.x, cx0[4]);  cx1[4]  = fmaf(e1w, vbb.x, cx1[4]);
      cx0[5]  = fmaf(e0w, vbb.y, cx0[5]);  cx1[5]  = fmaf(e1w, vbb.y, cx1[5]);
      cx0[6]  = fmaf(e0w, vbb.z, cx0[6]);  cx1[6]  = fmaf(e1w, vbb.z, cx1[6]);
      cx0[7]  = fmaf(e0w, vbb.w, cx0[7]);  cx1[7]  = fmaf(e1w, vbb.w, cx1[7]);
      cx0[8]  = fmaf(e0w, vc.x, cx0[8]);   cx1[8]  = fmaf(e1w, vc.x, cx1[8]);
      cx0[9]  = fmaf(e0w, vc.y, cx0[9]);   cx1[9]  = fmaf(e1w, vc.y, cx1[9]);
      cx0[10] = fmaf(e0w, vc.z, cx0[10]);  cx1[10] = fmaf(e1w, vc.z, cx1[10]);
      cx0[11] = fmaf(e0w, vc.w, cx0[11]);  cx1[11] = fmaf(e1w, vc.w, cx1[11]);
      cx0[12] = fmaf(e0w, vd.x, cx0[12]);  cx1[12] = fmaf(e1w, vd.x, cx1[12]);
      cx0[13] = fmaf(e0w, vd.y, cx0[13]);  cx1[13] = fmaf(e1w, vd.y, cx1[13]);
      cx0[14] = fmaf(e0w, vd.z, cx0[14]);  cx1[14] = fmaf(e1w, vd.z, cx1[14]);
      cx0[15] = fmaf(e0w, vd.w, cx0[15]);  cx1[15] = fmaf(e1w, vd.w, cx1[15]);
    }
    __syncthreads();
  }

  float* sden = sh;
  float* scx  = sh + 512;
#pragma unroll
  for (int ph = 0; ph < 2; ++ph) {
    sden[w * 64 + qi] = ph ? den1 : den0;
    const float* cxp = ph ? cx1 : cx0;
#pragma unroll
    for (int d = 0; d < 16; ++d) scx[(w * 64 + qi) * 17 + d] = cxp[d];
    __syncthreads();
    if (tid < 256) {
      int q2 = tid >> 2, jj = tid & 3;
      int l2 = qt * 128 + ph * 64 + q2;
      if (l2 < LL) {
        float dtot = 0.f, c0 = 0.f, c1 = 0.f, c2 = 0.f, c3 = 0.f;
#pragma unroll
        for (int u = 0; u < 8; ++u) {
          dtot += sden[u * 64 + q2];
          const float* cp = &scx[(u * 64 + q2) * 17 + jj * 4];
          c0 += cp[0]; c1 += cp[1]; c2 += cp[2]; c3 += cp[3];
        }
        float inv = 1.f / dtot;
        float* op = ws + WS_CTX + (l2 * SS + s) * 64 + a * 16 + jj * 4;
        *reinterpret_cast<float4*>(op) =
            make_float4(c0 * inv, c1 * inv, c2 * inv, c3 * inv);
      }
    }
    __syncthreads();
  }
}

// ---- K7a: out-proj + FFA + residual conv, one block per (l,s) -------------
__global__ __launch_bounds__(64) void k7a_comb(
    const float* __restrict__ W_fa1, const float* __restrict__ b_fa1,
    const float* __restrict__ W_fa2, const float* __restrict__ b_fa2,
    const float* __restrict__ b_rc, const float* __restrict__ b_out,
    float* __restrict__ ws) {
  int blk = blockIdx.x;
  int l = blk / SS, s = blk % SS;
  int b = l / NN, n = l % NN;
  int f = threadIdx.x;
  __shared__ float h2r[64], ctr[64], dsrL[64], trL[64];

  h2r[f] = ws[WS_H2 + ((b * SS + s) * NN + n) * 64 + f];
  ctr[f] = ws[WS_CTX + (l * SS + s) * 64 + f];
  __syncthreads();

  float dsr = b_out[f], res = b_rc[f];
  for (int q = 0; q < 64; ++q) {
    dsr = fmaf(ctr[q], ws[WS_WOT + q * 64 + f], dsr);
    res = fmaf(h2r[q], ws[WS_WRCT + q * 64 + f], res);
  }
  dsrL[f] = dsr;
  __syncthreads();

  float t = b_fa1[f];
  for (int q = 0; q < 64; ++q) t = fmaf(dsrL[q], W_fa1[q * 64 + f], t);
  trL[f] = fmaxf(t, 0.f);
  __syncthreads();

  float ff = b_fa2[f];
  for (int q = 0; q < 64; ++q) ff = fmaf(trL[q], W_fa2[q * 64 + f], ff);
  ws[WS_XFL + (l * SS + s) * 64 + f] = res + ff;
}

// ---- K7b: final conv — out[b,p,n] = sum_{s,q} comb[l][s][q]*W_fin[p][s][q] -
__global__ __launch_bounds__(320) void k7b_fin(
    const float* __restrict__ W_fin, const float* __restrict__ b_fin,
    const float* __restrict__ ws, float* __restrict__ out) {
  int blk = blockIdx.x;
  int b = blk / SS, p = blk % SS;
  int tid = threadIdx.x;
  __shared__ float wf[768];
  for (int i = tid; i < 768; i += 320) wf[i] = W_fin[p * 768 + i];
  __syncthreads();
  int n = tid;
  if (n < NN) {
    const float* cb = ws + WS_XFL + (b * NN + n) * 768;
    float a0 = 0.f, a1 = 0.f, a2 = 0.f, a3 = 0.f;
    for (int i = 0; i < 768; i += 4) {
      a0 = fmaf(cb[i], wf[i], a0);
      a1 = fmaf(cb[i + 1], wf[i + 1], a1);
      a2 = fmaf(cb[i + 2], wf[i + 2], a2);
      a3 = fmaf(cb[i + 3], wf[i + 3], a3);
    }
    out[(b * SS + p) * NN + n] = (a0 + a1) + (a2 + a3) + b_fin[p];
  }
}

extern "C" void kernel_launch(void* const* d_in, const int* in_sizes, int n_in,
                              void* d_out, int out_size, void* d_ws, size_t ws_size,
                              hipStream_t stream) {
  (void)in_sizes; (void)n_in; (void)out_size; (void)ws_size;
  const float* x     = (const float*)d_in[0];
  const float* cheb  = (const float*)d_in[1];
  const float* theta = (const float*)d_in[2];
  const float* Wex   = (const float*)d_in[3];
  const float* bex   = (const float*)d_in[4];
  const float* Weos  = (const float*)d_in[5];
  const float* beos  = (const float*)d_in[6];
  const float* U_x   = (const float*)d_in[7];
  const float* V_x   = (const float*)d_in[8];
  const float* b_x   = (const float*)d_in[9];
  const float* U_g   = (const float*)d_in[10];
  const float* V_g   = (const float*)d_in[11];
  const float* b_g   = (const float*)d_in[12];
  const float* W_ff1 = (const float*)d_in[13];
  const float* b_ff1 = (const float*)d_in[14];
  const float* W_ff2 = (const float*)d_in[15];
  const float* b_ff2 = (const float*)d_in[16];
  const float* W_tc  = (const float*)d_in[17];
  const float* b_tc  = (const float*)d_in[18];
  const float* W_rc  = (const float*)d_in[19];
  const float* b_rc  = (const float*)d_in[20];
  const float* W_in  = (const float*)d_in[21];
  const float* b_in  = (const float*)d_in[22];
  const float* W_out = (const float*)d_in[23];
  const float* b_out = (const float*)d_in[24];
  const float* W_fa1 = (const float*)d_in[25];
  const float* b_fa1 = (const float*)d_in[26];
  const float* W_fa2 = (const float*)d_in[27];
  const float* b_fa2 = (const float*)d_in[28];
  const float* W_fin = (const float*)d_in[29];
  const float* b_fin = (const float*)d_in[30];
  float* ws = (float*)d_ws;
  float* outp = (float*)d_out;

  k12_fused<<<3093, 320, 0, stream>>>(x, cheb, theta, Wex, bex, Weos, beos,
                                      W_rc, W_out, ws);
  k3_scan<<<1228, 384, 0, stream>>>(U_x, V_x, b_x, U_g, V_g, b_g,
                                    W_ff1, b_ff1, W_ff2, b_ff2, W_tc, b_tc, ws);
  k5_qkv<<<48 * 77, 256, 0, stream>>>(W_in, b_in, ws);
  k6_attn<<<480, 512, 0, stream>>>(ws);
  k7a_comb<<<LL * SS, 64, 0, stream>>>(W_fa1, b_fa1, W_fa2, b_fa2,
                                       b_rc, b_out, ws);
  k7b_fin<<<BB * SS, 320, 0, stream>>>(W_fin, b_fin, ws, outp);
}